// Round 8
// baseline (381.230 us; speedup 1.0000x reference)
//
#include <hip/hip_runtime.h>
#include <stdint.h>
#include <math.h>

// HierarchicalSoftmax: out[b, i*225+j] = softmax(x@W0+b0)[b,i] * softmax(x@W1+b1)[b,j], f<50257
//
// Pipeline (R8: single-term fp16 x (W fp16 x1024), 12 waves 2m x 6n -> acc[4][5]=80 AGPR;
//           LDS/K-step 214->146 KB, MFMA halved; finish uses aligned float4 stores):
//  1) hs_prep : W0,W1 fp32 [K][225] -> ws: per-K-tile images of W^T [480][BK] fp16 (x1024),
//               XOR-swizzled so GEMM can global_load_lds linearly and ds_read conflict-free.
//  2) hs_gemm : logits*1024 = (fp16)x @ (fp16)([W0|W1]*1024), fp32 acc, split-K partials.
//               Logit err ~5.6e-4 std (x-round + W-round) -> output absmax ~2e-4 << 1.47e-3.
//  3) hs_finish: reduce partials * 2^-10 + bias, per-head softmax, fused outer-product store.

#define BATCH   2048
#define KDIM    50257
#define LSZ     225
#define HOFF    240        // head1 column offset in padded logits
#define NPAD    480        // padded N: [0,225) = head0, [240,465) = head1, rest zero
#define BK      32
#define BM      128
#define NT      1571       // ceil(50257/32)
#define TILE_B  30720      // B tile bytes: 480 rows * 64B (fp16, single image)
#define A_BYTES 8192       // A tile bytes: 128 rows * 64B (fp16, single image)
#define BUF_B   38912      // TILE_B + A_BYTES
#define LDS_TOT 77824      // 2 * BUF_B (double buffer)
#define WSCALE  1024.0f    // W pre-scale: keeps fp16 weights out of denormal range

typedef __attribute__((ext_vector_type(8))) _Float16 f16x8;
typedef __attribute__((ext_vector_type(4))) float    f32x4;

__device__ __forceinline__ unsigned short f2h(float f) {    // fp32 -> fp16 bits (RNE)
  return __builtin_bit_cast(unsigned short, (_Float16)f);
}
// XOR swizzle: flip byte-offset bits 4-5 by row bits 1-2 -> frag ds_read_b128 is 2-way (free)
__device__ __forceinline__ int swzr(int r) { return ((r >> 1) & 3) << 4; }

// ---------------- prep: build swizzled, tiled fp16 W^T (scaled x1024) ----------------
__global__ __launch_bounds__(512) void hs_prep(const float* __restrict__ W0,
                                               const float* __restrict__ W1,
                                               unsigned char* __restrict__ wt) {
  const int kt = blockIdx.x;           // one K-tile per block
  const int k0 = kt * BK;
  unsigned char* tb = wt + (size_t)kt * TILE_B;
  for (int idx = threadIdx.x; idx < NPAD * 8; idx += 512) {
    const int n = idx >> 3, c4 = idx & 7;       // row n, 4-elem group c4
    const float* src = nullptr;
    if (n < HOFF) { if (n < LSZ) src = W0 + n; }
    else          { if (n - HOFF < LSZ) src = W1 + (n - HOFF); }
    unsigned short he[4];
#pragma unroll
    for (int e = 0; e < 4; ++e) {
      const int k = k0 + c4 * 4 + e;
      float v = (src != nullptr && k < KDIM) ? src[(size_t)k * LSZ] * WSCALE : 0.0f;
      he[e] = f2h(v);
    }
    const int jp = (c4 * 8) ^ swzr(n);
    *(ushort4*)(tb + n * 64 + jp) = make_ushort4(he[0], he[1], he[2], he[3]);
  }
}

// ---------------- GEMM: 128x480 tile, BK=32, 12 waves (2m x 6n), split-K ----------------
__global__ __launch_bounds__(768, 3) void hs_gemm(
    const float* __restrict__ x, const unsigned char* __restrict__ wt,
    float* __restrict__ partials, int ksplit, int tpc) {
  extern __shared__ __align__(16) unsigned char smem[];
  const int bid   = blockIdx.x;
  const int chunk = bid % ksplit;            // same-chunk blocks share XCD (bid%8 == chunk%8)
  const int mtile = bid / ksplit;
  const int t0 = chunk * tpc;
  int t1 = t0 + tpc; if (t1 > NT) t1 = NT;
  const int m0 = mtile * BM;
  const int tid = threadIdx.x;
  const int lane = tid & 63, wid = tid >> 6;
  const int wm = wid & 1, wn = wid >> 1;     // 2m x 6n; wave tile: 64 rows x 80 cols (uniform)
  const int jl  = (lane >> 4) * 16;          // frag k-offset bytes (8 f16)
  const int l15 = lane & 15;

  // A staging geometry: threads 0..511 cover row tid>>2, 8 k-elems at (tid&3)*8
  const int arow = tid >> 2, c8 = tid & 3;
  const bool astg = (tid < 512);
  const float* xr = x + (size_t)(m0 + arow) * KDIM + c8 * 8;
  const int aoff = arow * 64 + ((c8 * 16) ^ swzr(arow));

  f32x4 acc[4][5];
#pragma unroll
  for (int mf = 0; mf < 4; ++mf)
#pragma unroll
    for (int nf = 0; nf < 5; ++nf)
      acc[mf][nf] = f32x4{0.f, 0.f, 0.f, 0.f};

  auto stageB = [&](int kt, int buf) {   // 30 x 1KB wave-chunks, pre-swizzled in ws
    const unsigned char* src = wt + (size_t)kt * TILE_B + lane * 16;
    unsigned char* dstb = smem + buf * BUF_B;
#pragma unroll
    for (int c = 0; c < 3; ++c) {
      const int cc = wid + c * 12;
      if (cc < 30) {
        __builtin_amdgcn_global_load_lds(
            (const __attribute__((address_space(1))) unsigned int*)(src + cc * 1024),
            (__attribute__((address_space(3))) unsigned int*)(dstb + cc * 1024),
            16, 0, 0);
      }
    }
  };

  auto loadA = [&](int kt, f32x4& v0, f32x4& v1) {
    if (!astg) return;
    const int kb = kt * BK + c8 * 8;
    const float* p = xr + (size_t)kt * BK;
    if (kb + 8 <= KDIM) {
      __builtin_memcpy(&v0, p, 16);
      __builtin_memcpy(&v1, p + 4, 16);
    } else {
#pragma unroll
      for (int e = 0; e < 4; ++e) {
        v0[e] = (kb + e < KDIM)     ? p[e]     : 0.f;
        v1[e] = (kb + 4 + e < KDIM) ? p[4 + e] : 0.f;
      }
    }
  };

  auto writeA = [&](int buf, const f32x4& v0, const f32x4& v1) {
    if (!astg) return;
    unsigned char* ab = smem + buf * BUF_B + TILE_B;
    unsigned short he[8];
#pragma unroll
    for (int e = 0; e < 4; ++e) {
      he[e]     = f2h(v0[e]);
      he[4 + e] = f2h(v1[e]);
    }
    *(ushort4*)(ab + aoff)     = make_ushort4(he[0], he[1], he[2], he[3]);
    *(ushort4*)(ab + aoff + 8) = make_ushort4(he[4], he[5], he[6], he[7]);
  };

  auto compute = [&](int buf) {          // flat block: compiler pipelines ds_read/MFMA
    const unsigned char* bb = smem + buf * BUF_B;
    const unsigned char* ab = bb + TILE_B;
    f16x8 ah[4];
#pragma unroll
    for (int mf = 0; mf < 4; ++mf) {
      const int m = wm * 64 + mf * 16 + l15;
      const int off = m * 64 + (jl ^ swzr(m));
      ah[mf] = *(const f16x8*)(ab + off);
    }
#pragma unroll
    for (int nf = 0; nf < 5; ++nf) {
      const int n = wn * 80 + nf * 16 + l15;
      const int off = n * 64 + (jl ^ swzr(n));
      const f16x8 bw = *(const f16x8*)(bb + off);
#pragma unroll
      for (int mf = 0; mf < 4; ++mf)
        acc[mf][nf] = __builtin_amdgcn_mfma_f32_16x16x32_f16(ah[mf], bw, acc[mf][nf], 0, 0, 0);
    }
  };

  if (t0 < t1) {
    f32x4 v0, v1;
    stageB(t0, 0);
    loadA(t0, v0, v1);
    writeA(0, v0, v1);                  // implicit vmcnt wait on own loads
    __syncthreads();
    int buf = 0;
    for (int t = t0; t < t1; ++t) {
      const bool more = (t + 1 < t1);
      if (more) {                       // prefetch next tile before compute (2-phase)
        stageB(t + 1, buf ^ 1);
        loadA(t + 1, v0, v1);
      }
      compute(buf);
      if (more) writeA(buf ^ 1, v0, v1);
      __syncthreads();
      buf ^= 1;
    }
  }

  // epilogue: C/D frag map (m89): lane l, reg r -> row=(l>>4)*4+r, col=l&15
  float* pout = partials + ((size_t)chunk * BATCH + m0) * NPAD;
#pragma unroll
  for (int mf = 0; mf < 4; ++mf)
#pragma unroll
    for (int nf = 0; nf < 5; ++nf)
#pragma unroll
      for (int r = 0; r < 4; ++r) {
        const int row = wm * 64 + mf * 16 + (lane >> 4) * 4 + r;
        const int col = wn * 80 + nf * 16 + l15;
        pout[(size_t)row * NPAD + col] = acc[mf][nf][r];
      }
}

// ---------------- finish: reduce + bias + softmax x2 + outer-product store ----------------
__global__ __launch_bounds__(512) void hs_finish(
    const float* __restrict__ partials, const float* __restrict__ b0,
    const float* __restrict__ b1, float* __restrict__ out, int ksplit) {
  const int b = blockIdx.x;
  __shared__ float lg[NPAD];
  __shared__ float red[4];          // {max0, 1/sum0, max1, 1/sum1}
  const int tid = threadIdx.x;
  if (tid < NPAD) {
    float v = 0.f;
    for (int c = 0; c < ksplit; ++c)
      v += partials[((size_t)c * BATCH + b) * NPAD + tid];
    v *= (1.0f / WSCALE);           // undo W pre-scale
    if (tid < LSZ) v += b0[tid];
    else if (tid >= HOFF && tid < HOFF + LSZ) v += b1[tid - HOFF];
    lg[tid] = v;
  }
  __syncthreads();
  const int wid = tid >> 6, lane = tid & 63;
  if (wid < 2) {                    // wave 0 -> head0, wave 1 -> head1
    const int base = wid * HOFF;
    float m = -1e30f;
    for (int i = lane; i < LSZ; i += 64) m = fmaxf(m, lg[base + i]);
#pragma unroll
    for (int s = 32; s; s >>= 1) m = fmaxf(m, __shfl_xor(m, s));
    float sum = 0.f;
    for (int i = lane; i < LSZ; i += 64) sum += __expf(lg[base + i] - m);
#pragma unroll
    for (int s = 32; s; s >>= 1) sum += __shfl_xor(sum, s);
    if (lane == 0) { red[wid * 2] = m; red[wid * 2 + 1] = 1.0f / sum; }
  }
  __syncthreads();
  if (tid < NPAD) {                 // own-index read-modify-write: no extra barrier needed
    const int h = (tid >= HOFF) ? 1 : 0;
    const int off = tid - (h ? HOFF : 0);
    float hv = 0.f;
    if (off < LSZ) hv = __expf(lg[tid] - red[2 * h]) * red[2 * h + 1];
    lg[tid] = hv;
  }
  __syncthreads();
  const size_t ob = (size_t)b * KDIM;
  // aligned float4 body: (ob + h4) % 4 == 0 since ob % 4 == b & 3
  const int h4 = (4 - (b & 3)) & 3;
  if (tid < h4) out[ob + tid] = lg[0] * lg[HOFF + tid];   // head (i = 0 always: h4 <= 3)
  const int nbody = (KDIM - h4) >> 2;                      // # of float4 stores
  for (int q = tid; q < nbody; q += 512) {
    const int f = h4 + q * 4;
    int i = f / LSZ;                 // compiler magic-mul
    int j = f - i * LSZ;
    float4 v;
    v.x = lg[i] * lg[HOFF + j]; if (++j == LSZ) { j = 0; ++i; }
    v.y = lg[i] * lg[HOFF + j]; if (++j == LSZ) { j = 0; ++i; }
    v.z = lg[i] * lg[HOFF + j]; if (++j == LSZ) { j = 0; ++i; }
    v.w = lg[i] * lg[HOFF + j];
    *(float4*)(out + ob + f) = v;
  }
  const int be = h4 + nbody * 4;     // tail: < 4 elems
  if (tid < KDIM - be) {
    const int f = be + tid;
    const int i = f / LSZ;
    const int j = f - i * LSZ;
    out[ob + f] = lg[i] * lg[HOFF + j];
  }
}

extern "C" void kernel_launch(void* const* d_in, const int* in_sizes, int n_in,
                              void* d_out, int out_size, void* d_ws, size_t ws_size,
                              hipStream_t stream) {
  (void)in_sizes; (void)n_in; (void)out_size;
  const float* x  = (const float*)d_in[0];
  const float* W0 = (const float*)d_in[1];
  const float* W1 = (const float*)d_in[2];
  const float* b0 = (const float*)d_in[3];
  const float* b1 = (const float*)d_in[4];
  float* out = (float*)d_out;
  unsigned char* ws = (unsigned char*)d_ws;

  const size_t WT_BYTES  = (size_t)NT * TILE_B;            // 48.3 MB
  const size_t PER_CHUNK = (size_t)BATCH * NPAD * sizeof(float);
  int ksplit = 16;
  if (ws_size > WT_BYTES) {
    const int kmax = (int)((ws_size - WT_BYTES) / PER_CHUNK);
    if (ksplit > kmax) ksplit = kmax;
  } else {
    ksplit = 1;
  }
  if (ksplit < 1) ksplit = 1;
  float* partials = (float*)(ws + WT_BYTES);
  const int tpc = (NT + ksplit - 1) / ksplit;

  hs_prep<<<dim3(NT), dim3(512), 0, stream>>>(W0, W1, ws);
  hipFuncSetAttribute((const void*)hs_gemm,
                      hipFuncAttributeMaxDynamicSharedMemorySize, LDS_TOT);
  hs_gemm<<<dim3(16 * ksplit), dim3(768), LDS_TOT, stream>>>(x, ws, partials, ksplit, tpc);
  hs_finish<<<dim3(BATCH), dim3(512), 0, stream>>>(partials, b0, b1, out, ksplit);
}

// Round 9
// 324.258 us; speedup vs baseline: 1.1757x; 1.1757x over previous
//
#include <hip/hip_runtime.h>
#include <stdint.h>
#include <math.h>

// HierarchicalSoftmax: out[b, i*225+j] = softmax(x@W0+b0)[b,i] * softmax(x@W1+b1)[b,j], f<50257
//
// Pipeline (R9: BK=64 halves iteration count -- per-iter fixed cost ~2700cyc was dominant;
//           8 waves / acc[2][15] proven register shape; single-term fp16; scalar finish):
//  1) hs_prep : W0,W1 fp32 [K][225] -> ws: per-K-tile images of W^T [480][128B] fp16 (x1024),
//               row-XOR-swizzled (byte ^= (row&7)<<4 on 16B blocks) so GEMM stages linearly
//               via global_load_lds and ds_read_b128 frags are conflict-free.
//  2) hs_gemm : logits*1024 = (fp16)x @ (fp16)([W0|W1]*1024), fp32 acc, split-K partials.
//  3) hs_finish: reduce partials * 2^-10 + bias, per-head softmax, fused outer-product store
//               (stride-1 LDS reads, proven R5 version).

#define BATCH   2048
#define KDIM    50257
#define LSZ     225
#define HOFF    240        // head1 column offset in padded logits
#define NPAD    480        // padded N: [0,225) = head0, [240,465) = head1, rest zero
#define BK      64
#define BM      128
#define NT      786        // ceil(50257/64)
#define TILE_B  61440      // B tile bytes: 480 rows * 128B (fp16)
#define A_BYTES 16384      // A tile bytes: 128 rows * 128B (fp16)
#define BUF_B   77824      // TILE_B + A_BYTES
#define LDS_TOT 155648     // 2 * BUF_B (double buffer), fits 160KB
#define WSCALE  1024.0f    // W pre-scale: keeps fp16 weights out of denormal range

typedef __attribute__((ext_vector_type(8))) _Float16 f16x8;
typedef __attribute__((ext_vector_type(4))) float    f32x4;

__device__ __forceinline__ unsigned short f2h(float f) {    // fp32 -> fp16 bits (RNE)
  return __builtin_bit_cast(unsigned short, (_Float16)f);
}
// 128B-row swizzle: XOR 16B-block index by (row&7) -> 16-row frag reads = 2-way (free)
__device__ __forceinline__ int swz8(int r) { return (r & 7) << 4; }

// ---------------- prep: build swizzled, tiled fp16 W^T (scaled x1024) ----------------
__global__ __launch_bounds__(512) void hs_prep(const float* __restrict__ W0,
                                               const float* __restrict__ W1,
                                               unsigned char* __restrict__ wt) {
  const int kt = blockIdx.x;           // one K-tile (64 k's) per block
  const int k0 = kt * BK;
  unsigned char* tb = wt + (size_t)kt * TILE_B;
  for (int idx = threadIdx.x; idx < NPAD * 16; idx += 512) {
    const int n = idx >> 4, c4 = idx & 15;      // row n, 4-elem (8B) group c4
    const float* src = nullptr;
    if (n < HOFF) { if (n < LSZ) src = W0 + n; }
    else          { if (n - HOFF < LSZ) src = W1 + (n - HOFF); }
    unsigned short he[4];
#pragma unroll
    for (int e = 0; e < 4; ++e) {
      const int k = k0 + c4 * 4 + e;
      float v = (src != nullptr && k < KDIM) ? src[(size_t)k * LSZ] * WSCALE : 0.0f;
      he[e] = f2h(v);
    }
    const int jp = (c4 * 8) ^ swz8(n);          // XOR permutes 16B blocks, keeps 8B phase
    *(ushort4*)(tb + n * 128 + jp) = make_ushort4(he[0], he[1], he[2], he[3]);
  }
}

// ---------------- GEMM: 128x480 tile, BK=64, 8 waves (4m x 2n), split-K ----------------
__global__ __launch_bounds__(512, 2) void hs_gemm(
    const float* __restrict__ x, const unsigned char* __restrict__ wt,
    float* __restrict__ partials, int ksplit, int tpc) {
  extern __shared__ __align__(16) unsigned char smem[];
  const int bid   = blockIdx.x;
  const int chunk = bid % ksplit;            // same-chunk blocks cluster on XCDs (wt L2 reuse)
  const int mtile = bid / ksplit;
  const int t0 = chunk * tpc;
  int t1 = t0 + tpc; if (t1 > NT) t1 = NT;
  const int m0 = mtile * BM;
  const int tid = threadIdx.x;
  const int lane = tid & 63, wid = tid >> 6;
  const int wm = wid >> 1, wn = wid & 1;     // wave tile: 32 rows x 240 cols
  const int jl  = (lane >> 4) * 16;          // frag k-offset bytes within a 64B k-half
  const int l15 = lane & 15;

  // A staging geometry: thread covers row tid>>2, 16 k-elems at (tid&3)*16
  const int arow = tid >> 2, c16 = tid & 3;
  const float* xr = x + (size_t)(m0 + arow) * KDIM + c16 * 16;

  f32x4 acc[2][15];
#pragma unroll
  for (int mf = 0; mf < 2; ++mf)
#pragma unroll
    for (int nf = 0; nf < 15; ++nf)
      acc[mf][nf] = f32x4{0.f, 0.f, 0.f, 0.f};

  auto stageB = [&](int kt, int buf) {   // 60 x 1KB wave-chunks, pre-swizzled in ws
    const unsigned char* src = wt + (size_t)kt * TILE_B + lane * 16;
    unsigned char* dstb = smem + buf * BUF_B;
#pragma unroll
    for (int c = 0; c < 8; ++c) {
      const int cc = wid + c * 8;
      if (cc < 60) {
        __builtin_amdgcn_global_load_lds(
            (const __attribute__((address_space(1))) unsigned int*)(src + cc * 1024),
            (__attribute__((address_space(3))) unsigned int*)(dstb + cc * 1024),
            16, 0, 0);
      }
    }
  };

  auto loadA = [&](int kt, f32x4& v0, f32x4& v1, f32x4& v2, f32x4& v3) {
    const int kb = kt * BK + c16 * 16;
    const float* p = xr + (size_t)kt * BK;
    if (kb + 16 <= KDIM) {
      __builtin_memcpy(&v0, p, 16);      __builtin_memcpy(&v1, p + 4, 16);
      __builtin_memcpy(&v2, p + 8, 16);  __builtin_memcpy(&v3, p + 12, 16);
    } else {                              // only the last K-tile takes this path
#pragma unroll
      for (int e = 0; e < 4; ++e) {
        v0[e] = (kb + e < KDIM)      ? p[e]      : 0.f;
        v1[e] = (kb + 4 + e < KDIM)  ? p[4 + e]  : 0.f;
        v2[e] = (kb + 8 + e < KDIM)  ? p[8 + e]  : 0.f;
        v3[e] = (kb + 12 + e < KDIM) ? p[12 + e] : 0.f;
      }
    }
  };

  auto writeA = [&](int buf, const f32x4& v0, const f32x4& v1,
                    const f32x4& v2, const f32x4& v3) {
    unsigned char* ab = smem + buf * BUF_B + TILE_B + arow * 128;
    unsigned short he[16];
#pragma unroll
    for (int e = 0; e < 4; ++e) {
      he[e]      = f2h(v0[e]);
      he[4 + e]  = f2h(v1[e]);
      he[8 + e]  = f2h(v2[e]);
      he[12 + e] = f2h(v3[e]);
    }
    const int s = swz8(arow);
    __builtin_memcpy(ab + ((c16 * 32) ^ s),      he,     16);   // ds_write_b128 x2
    __builtin_memcpy(ab + ((c16 * 32 + 16) ^ s), he + 8, 16);
  };

  auto compute = [&](int buf) {          // flat block: compiler pipelines ds_read/MFMA
    const unsigned char* bb = smem + buf * BUF_B;
    const unsigned char* ab = bb + TILE_B;
#pragma unroll
    for (int ks = 0; ks < 2; ++ks) {     // two K=32 sub-steps per 64-wide tile
      const int kbyte = ks * 64 + jl;
      f16x8 ah[2];
#pragma unroll
      for (int mf = 0; mf < 2; ++mf) {
        const int m = wm * 32 + mf * 16 + l15;
        ah[mf] = *(const f16x8*)(ab + m * 128 + (kbyte ^ swz8(m)));
      }
#pragma unroll
      for (int nf = 0; nf < 15; ++nf) {
        const int n = wn * 240 + nf * 16 + l15;
        const f16x8 bw = *(const f16x8*)(bb + n * 128 + (kbyte ^ swz8(n)));
        acc[0][nf] = __builtin_amdgcn_mfma_f32_16x16x32_f16(ah[0], bw, acc[0][nf], 0, 0, 0);
        acc[1][nf] = __builtin_amdgcn_mfma_f32_16x16x32_f16(ah[1], bw, acc[1][nf], 0, 0, 0);
      }
    }
  };

  if (t0 < t1) {
    f32x4 v0, v1, v2, v3;
    stageB(t0, 0);
    loadA(t0, v0, v1, v2, v3);
    writeA(0, v0, v1, v2, v3);          // implicit vmcnt wait on own loads
    __syncthreads();
    int buf = 0;
    for (int t = t0; t < t1; ++t) {
      const bool more = (t + 1 < t1);
      if (more) {                       // prefetch next tile before compute (2-phase)
        stageB(t + 1, buf ^ 1);
        loadA(t + 1, v0, v1, v2, v3);
      }
      compute(buf);
      if (more) writeA(buf ^ 1, v0, v1, v2, v3);
      __syncthreads();
      buf ^= 1;
    }
  }

  // epilogue: C/D frag map (m89): lane l, reg r -> row=(l>>4)*4+r, col=l&15
  float* pout = partials + ((size_t)chunk * BATCH + m0) * NPAD;
#pragma unroll
  for (int mf = 0; mf < 2; ++mf)
#pragma unroll
    for (int nf = 0; nf < 15; ++nf)
#pragma unroll
      for (int r = 0; r < 4; ++r) {
        const int row = wm * 32 + mf * 16 + (lane >> 4) * 4 + r;
        const int col = wn * 240 + nf * 16 + l15;
        pout[(size_t)row * NPAD + col] = acc[mf][nf][r];
      }
}

// ---------------- finish: reduce + bias + softmax x2 + outer-product store ----------------
__global__ __launch_bounds__(512) void hs_finish(
    const float* __restrict__ partials, const float* __restrict__ b0,
    const float* __restrict__ b1, float* __restrict__ out, int ksplit) {
  const int b = blockIdx.x;
  __shared__ float lg[NPAD];
  __shared__ float red[4];          // {max0, 1/sum0, max1, 1/sum1}
  const int tid = threadIdx.x;
  if (tid < NPAD) {
    float v = 0.f;
    for (int c = 0; c < ksplit; ++c)
      v += partials[((size_t)c * BATCH + b) * NPAD + tid];
    v *= (1.0f / WSCALE);           // undo W pre-scale
    if (tid < LSZ) v += b0[tid];
    else if (tid >= HOFF && tid < HOFF + LSZ) v += b1[tid - HOFF];
    lg[tid] = v;
  }
  __syncthreads();
  const int wid = tid >> 6, lane = tid & 63;
  if (wid < 2) {                    // wave 0 -> head0, wave 1 -> head1
    const int base = wid * HOFF;
    float m = -1e30f;
    for (int i = lane; i < LSZ; i += 64) m = fmaxf(m, lg[base + i]);
#pragma unroll
    for (int s = 32; s; s >>= 1) m = fmaxf(m, __shfl_xor(m, s));
    float sum = 0.f;
    for (int i = lane; i < LSZ; i += 64) sum += __expf(lg[base + i] - m);
#pragma unroll
    for (int s = 32; s; s >>= 1) sum += __shfl_xor(sum, s);
    if (lane == 0) { red[wid * 2] = m; red[wid * 2 + 1] = 1.0f / sum; }
  }
  __syncthreads();
  if (tid < NPAD) {                 // own-index read-modify-write: no extra barrier needed
    const int h = (tid >= HOFF) ? 1 : 0;
    const int off = tid - (h ? HOFF : 0);
    float hv = 0.f;
    if (off < LSZ) hv = __expf(lg[tid] - red[2 * h]) * red[2 * h + 1];
    lg[tid] = hv;
  }
  __syncthreads();
  const size_t ob = (size_t)b * KDIM;
  for (int f = tid; f < KDIM; f += 512) {
    const int i = f / LSZ;          // compiler magic-mul; stride-1 LDS reads (conflict-free)
    const int j = f - i * LSZ;
    out[ob + f] = lg[i] * lg[HOFF + j];
  }
}

extern "C" void kernel_launch(void* const* d_in, const int* in_sizes, int n_in,
                              void* d_out, int out_size, void* d_ws, size_t ws_size,
                              hipStream_t stream) {
  (void)in_sizes; (void)n_in; (void)out_size;
  const float* x  = (const float*)d_in[0];
  const float* W0 = (const float*)d_in[1];
  const float* W1 = (const float*)d_in[2];
  const float* b0 = (const float*)d_in[3];
  const float* b1 = (const float*)d_in[4];
  float* out = (float*)d_out;
  unsigned char* ws = (unsigned char*)d_ws;

  const size_t WT_BYTES  = (size_t)NT * TILE_B;            // 48.3 MB
  const size_t PER_CHUNK = (size_t)BATCH * NPAD * sizeof(float);
  int ksplit = 16;
  if (ws_size > WT_BYTES) {
    const int kmax = (int)((ws_size - WT_BYTES) / PER_CHUNK);
    if (ksplit > kmax) ksplit = kmax;
  } else {
    ksplit = 1;
  }
  if (ksplit < 1) ksplit = 1;
  float* partials = (float*)(ws + WT_BYTES);
  const int tpc = (NT + ksplit - 1) / ksplit;

  hs_prep<<<dim3(NT), dim3(512), 0, stream>>>(W0, W1, ws);
  hipFuncSetAttribute((const void*)hs_gemm,
                      hipFuncAttributeMaxDynamicSharedMemorySize, LDS_TOT);
  hs_gemm<<<dim3(16 * ksplit), dim3(512), LDS_TOT, stream>>>(x, ws, partials, ksplit, tpc);
  hs_finish<<<dim3(BATCH), dim3(512), 0, stream>>>(partials, b0, b1, out, ksplit);
}